// Round 6
// baseline (403.560 us; speedup 1.0000x reference)
//
#include <hip/hip_runtime.h>
#include <math.h>

#define HDIM 60
#define EPSC 0.01f
#define ALPHAC 0.1f

// ---------------------------------------------------------------------------
// Kernel 1 (prep, 1 block): (a) transpose W2 -> d_ws[0..3599] (W2T[i][j] =
// W2[j][i]), (b) compute h_0 = ICNN(Xref) -> d_ws[3600].
// ---------------------------------------------------------------------------
__global__ void dho_prep_kernel(const float* __restrict__ Xref,
                                const float* __restrict__ W1, const float* __restrict__ b1,
                                const float* __restrict__ W2, const float* __restrict__ b2,
                                const float* __restrict__ W3, const float* __restrict__ b3,
                                const float* __restrict__ Wim2, const float* __restrict__ Wim3,
                                float* __restrict__ ws)
{
    const int t = threadIdx.x;
    // transpose: ws[i*60 + j] = W2[j*60 + i]
    for (int k = t; k < HDIM * HDIM; k += 64) {
        int i = k / HDIM;
        int j = k - i * HDIM;
        ws[k] = W2[j * HDIM + i];
    }

    __shared__ float z1s[HDIM];
    __shared__ float z2s[HDIM];
    const float x0 = Xref[0], x1 = Xref[1];
    if (t < HDIM) {
        float a = W1[2 * t] * x0 + W1[2 * t + 1] * x1 + b1[t];
        float e = expf(-fabsf(a));
        z1s[t] = logf(1.0f + e) + fmaxf(a, 0.0f);
    }
    __syncthreads();
    if (t < HDIM) {
        float a = b2[t] + Wim2[2 * t] * x0 + Wim2[2 * t + 1] * x1;
        for (int i = 0; i < HDIM; ++i) a += W2[t * HDIM + i] * z1s[i];
        float e = expf(-fabsf(a));
        z2s[t] = logf(1.0f + e) + fmaxf(a, 0.0f);
    }
    __syncthreads();
    if (t == 0) {
        float a = b3[0] + Wim3[0] * x0 + Wim3[1] * x1;
        for (int j = 0; j < HDIM; ++j) a += W3[j] * z2s[j];
        float e = expf(-fabsf(a));
        ws[HDIM * HDIM] = logf(1.0f + e) + fmaxf(a, 0.0f);
    }
}

// ---------------------------------------------------------------------------
// Kernel 2: column-streamed two-pass formulation. One thread per sample.
// Pass 1 streams W2T rows (W2 columns): acc[j] += z1_i * W2T[i][j], with
// z1_i computed on the fly -> NO persistent z1 array. Softplus block turns
// acc[] into tj[] in place. Pass 2 streams W2T again: gi = sum_j tj*W2T[i][j],
// z1_i/s1_i recomputed (~9 instr). Peak live ~90 floats -> fits arch VGPRs
// under the compiler's 128 cap, no AGPR round-trips (R4/R5's 2.5x inflation).
// All weight reads are wave-uniform in uniform control flow -> scalar loads
// (SGPR operands), no LDS, no __syncthreads. Reg arrays only indexed from
// fully-unrolled loops.
// ---------------------------------------------------------------------------
__global__ __launch_bounds__(256, 2) void dho_main_kernel(
    const float* __restrict__ X, const float* __restrict__ U,
    const float* __restrict__ W1, const float* __restrict__ b1,
    const float* __restrict__ W2T, const float* __restrict__ b2,
    const float* __restrict__ W3, const float* __restrict__ Wim2,
    const float* __restrict__ W_fnn, const float* __restrict__ W_gnn,
    const float* __restrict__ b_gnn, const float* __restrict__ b3,
    const float* __restrict__ Wim3, const float* __restrict__ Xref,
    const float* __restrict__ h0p,
    float* __restrict__ out, int N)
{
    const int n_raw = blockIdx.x * 256 + threadIdx.x;
    const int n = n_raw < N ? n_raw : N - 1;    // clamp: uniform control flow

    const float2 x = ((const float2*)X)[n];
    const float  u = U[n];

    float acc[HDIM];
#pragma unroll
    for (int j = 0; j < HDIM; ++j) acc[j] = 0.0f;

    // ---- pass 1: acc[j] = sum_i W2[j][i] * z1_i  (stream W2 columns) ----
#pragma unroll 1
    for (int i = 0; i < HDIM; ++i) {
        float w0 = W1[2 * i], w1v = W1[2 * i + 1], bb = b1[i];
        float a1  = fmaf(w0, x.x, fmaf(w1v, x.y, bb));
        float e1  = __expf(-fabsf(a1));
        float z1i = __logf(1.0f + e1) + fmaxf(a1, 0.0f);
        const float* col = W2T + i * HDIM;      // wave-uniform address
#pragma unroll
        for (int j = 0; j < HDIM; ++j)
            acc[j] = fmaf(z1i, col[j], acc[j]); // v_fmac v, s, v
    }

    // ---- softplus block: acc[j] -> tj[j] in place; a3acc, q0, q1 ----
    float a3acc = 0.0f, q0 = 0.0f, q1 = 0.0f;
#pragma unroll
    for (int j = 0; j < HDIM; ++j) {
        float wi0 = Wim2[2 * j], wi1 = Wim2[2 * j + 1];
        float a2  = fmaf(wi0, x.x, fmaf(wi1, x.y, acc[j] + b2[j]));
        float e   = __expf(-fabsf(a2));
        float inv = __builtin_amdgcn_rcpf(1.0f + e);
        float z2  = __logf(1.0f + e) + fmaxf(a2, 0.0f);
        float s2  = (a2 >= 0.0f ? 1.0f : e) * inv;
        float w3j = W3[j];
        a3acc = fmaf(w3j, z2, a3acc);
        float tj = w3j * s2;
        q0 = fmaf(tj, wi0, q0);
        q1 = fmaf(tj, wi1, q1);
        acc[j] = tj;
    }

    // ---- output layer ----
    const float wim3_0 = Wim3[0], wim3_1 = Wim3[1];
    float a3   = a3acc + b3[0] + wim3_0 * x.x + wim3_1 * x.y;
    float e3   = __expf(-fabsf(a3));
    float inv3 = __builtin_amdgcn_rcpf(1.0f + e3);
    float hX   = __logf(1.0f + e3) + fmaxf(a3, 0.0f);
    float s3   = (a3 >= 0.0f ? 1.0f : e3) * inv3;

    float h = hX - h0p[0];
    float sigma, sigp;
    if (h >= 1.0f)      { sigma = h - 0.5f;     sigp = 1.0f; }
    else if (h > 0.0f)  { sigma = 0.5f * h * h; sigp = h;    }
    else                { sigma = 0.0f;         sigp = 0.0f; }

    float dx0 = x.x - Xref[0], dx1 = x.y - Xref[1];
    float V = sigma + EPSC * (dx0 * dx0 + dx1 * dx1);

    // ---- pass 2: gi = sum_j tj[j] * W2[j][i]; fold into sum0/sum1 ----
    float sum0 = 0.0f, sum1 = 0.0f;
#pragma unroll 1
    for (int i = 0; i < HDIM; ++i) {
        float w0 = W1[2 * i], w1v = W1[2 * i + 1], bb = b1[i];
        float a1 = fmaf(w0, x.x, fmaf(w1v, x.y, bb));
        float e1 = __expf(-fabsf(a1));
        float s1 = (a1 >= 0.0f ? 1.0f : e1) * __builtin_amdgcn_rcpf(1.0f + e1);
        const float* col = W2T + i * HDIM;      // wave-uniform address
        float g0 = 0.0f, g1v = 0.0f, g2 = 0.0f, g3 = 0.0f;
#pragma unroll
        for (int j = 0; j < HDIM; j += 4) {     // 4 chains: break fma latency
            g0  = fmaf(acc[j + 0], col[j + 0], g0);
            g1v = fmaf(acc[j + 1], col[j + 1], g1v);
            g2  = fmaf(acc[j + 2], col[j + 2], g2);
            g3  = fmaf(acc[j + 3], col[j + 3], g3);
        }
        float gi = (g0 + g1v) + (g2 + g3);
        float c  = gi * s1;
        sum0 = fmaf(c, w0, sum0);
        sum1 = fmaf(c, w1v, sum1);
    }

    float dh0 = s3 * (wim3_0 + q0 + sum0);
    float dh1 = s3 * (wim3_1 + q1 + sum1);

    float dV0 = sigp * dh0 + 2.0f * EPSC * dx0;
    float dV1 = sigp * dh1 + 2.0f * EPSC * dx1;

    // ---- dynamics + correction ----
    float f0  = W_fnn[0] * x.x + W_fnn[1] * x.y;
    float f1  = W_fnn[2] * x.x + W_fnn[3] * x.y;
    float gg0 = W_gnn[0] * x.x + W_gnn[1] * x.y + b_gnn[0];
    float gg1 = W_gnn[2] * x.x + W_gnn[3] * x.y + b_gnn[1];

    float sc  = dV0 * f0 + dV1 * f1 + ALPHAC * V - fabsf(dV0 * gg0 + dV1 * gg1);
    float nrm = dV0 * dV0 + dV1 * dV1;
    float rr  = fmaxf(sc, 0.0f) * __builtin_amdgcn_rcpf(nrm);

    float o0 = f0 - dV0 * rr + gg0 * u;
    float o1 = f1 - dV1 * rr + gg1 * u;
    if (n_raw < N) ((float2*)out)[n] = make_float2(o0, o1);
}

extern "C" void kernel_launch(void* const* d_in, const int* in_sizes, int n_in,
                              void* d_out, int out_size, void* d_ws, size_t ws_size,
                              hipStream_t stream) {
    // 0:X 1:U 2:Xref 3:W_fnn 4:W_gnn 5:b_gnn 6:W1 7:b1 8:W2 9:b2 10:W3 11:b3 12:Wim2 13:Wim3
    const float* X     = (const float*)d_in[0];
    const float* U     = (const float*)d_in[1];
    const float* Xref  = (const float*)d_in[2];
    const float* W_fnn = (const float*)d_in[3];
    const float* W_gnn = (const float*)d_in[4];
    const float* b_gnn = (const float*)d_in[5];
    const float* W1    = (const float*)d_in[6];
    const float* b1    = (const float*)d_in[7];
    const float* W2    = (const float*)d_in[8];
    const float* b2    = (const float*)d_in[9];
    const float* W3    = (const float*)d_in[10];
    const float* b3    = (const float*)d_in[11];
    const float* Wim2  = (const float*)d_in[12];
    const float* Wim3  = (const float*)d_in[13];

    const int N = in_sizes[0] / 2;
    float* ws   = (float*)d_ws;        // [0..3599] W2T, [3600] h0
    float* W2T  = ws;
    float* h0   = ws + HDIM * HDIM;
    float* out  = (float*)d_out;

    dho_prep_kernel<<<1, 64, 0, stream>>>(Xref, W1, b1, W2, b2, W3, b3, Wim2, Wim3, ws);

    const int blocks = (N + 255) / 256;
    dho_main_kernel<<<blocks, 256, 0, stream>>>(
        X, U, W1, b1, W2T, b2, W3, Wim2,
        W_fnn, W_gnn, b_gnn, b3, Wim3, Xref, h0,
        out, N);
}

// Round 7
// 325.087 us; speedup vs baseline: 1.2414x; 1.2414x over previous
//
#include <hip/hip_runtime.h>
#include <math.h>

#define H 60
#define EPSC 0.01f
#define ALPHAC 0.1f

typedef __attribute__((ext_vector_type(8)))  __bf16        bf16x8;
typedef __attribute__((ext_vector_type(4)))  float         f32x4;
typedef __attribute__((ext_vector_type(4)))  unsigned int  uint4v;

// ws layout (bytes):
//   [0, 24576)      A1 frags  ushort[12288]  (GEMM1 A-operand: W2 rows,   m=j, k=i)
//   [24576, 49152)  A2 frags  ushort[12288]  (GEMM2 A-operand: W2T rows,  m=i, k=j)
//   [49152, 50176)  jconst    float4[64]     (b2, Wim2_0, Wim2_1, W3) zero-padded
//   [50176, 51200)  w1b1      float4[64]     (W1_0, W1_1, b1, 0) zero-padded
//   [51200, 51204)  h0        float
#define WS_A2_US   12288
#define WS_JC_B    49152
#define WS_WB_B    50176
#define WS_H0_B    51200

// ---------------------------------------------------------------------------
// Prep kernel (1 block, 256 thr): split W2 into 3 bf16 truncation levels and
// lay the pieces out in MFMA fragment order for both GEMMs; pack per-j and
// per-i constant float4 tables (zero-padded to 64); compute h0.
// Fragment order (16x16x32 bf16): frag id f=(sig*4+tile)*2+kt; lane L owns
// element b at [m = 16*tile + (L&15)][k = 32*kt + 8*(L>>4) + b].
// ---------------------------------------------------------------------------
__global__ void dho_prep(const float* __restrict__ Xref, const float* __restrict__ W1,
                         const float* __restrict__ b1, const float* __restrict__ W2,
                         const float* __restrict__ b2, const float* __restrict__ W3,
                         const float* __restrict__ b3, const float* __restrict__ Wim2,
                         const float* __restrict__ Wim3, void* __restrict__ wsv)
{
    unsigned short* A1 = (unsigned short*)wsv;
    unsigned short* A2 = A1 + WS_A2_US;
    float4* jc  = (float4*)((char*)wsv + WS_JC_B);
    float4* wb  = (float4*)((char*)wsv + WS_WB_B);
    float*  h0o = (float*)((char*)wsv + WS_H0_B);
    const int t = threadIdx.x;

    for (int idx = t; idx < 24576; idx += 256) {
        int which = idx >= 12288;           // 0: A1 (W2), 1: A2 (W2T)
        int rem   = which ? idx - 12288 : idx;
        int fid   = rem >> 9;
        int lane  = (rem >> 3) & 63;
        int b     = rem & 7;
        int sig   = fid >> 3;
        int tile  = (fid >> 1) & 3;
        int kt    = fid & 1;
        int m = 16 * tile + (lane & 15);
        int k = 32 * kt + 8 * (lane >> 4) + b;
        int j = which ? k : m;
        int i = which ? m : k;
        float w = (j < H && i < H) ? W2[j * H + i] : 0.0f;
        unsigned u0 = __float_as_uint(w) & 0xFFFF0000u;
        float r1 = w - __uint_as_float(u0);
        unsigned u1 = __float_as_uint(r1) & 0xFFFF0000u;
        float r2 = r1 - __uint_as_float(u1);
        unsigned u2 = __float_as_uint(r2) & 0xFFFF0000u;
        unsigned sel = (sig == 0) ? u0 : (sig == 1 ? u1 : u2);
        (which ? A2 : A1)[rem] = (unsigned short)(sel >> 16);
    }
    if (t < 64) {
        if (t < H) {
            jc[t] = make_float4(b2[t], Wim2[2 * t], Wim2[2 * t + 1], W3[t]);
            wb[t] = make_float4(W1[2 * t], W1[2 * t + 1], b1[t], 0.0f);
        } else {
            jc[t] = make_float4(0.f, 0.f, 0.f, 0.f);
            wb[t] = make_float4(0.f, 0.f, 0.f, 0.f);
        }
    }
    // h0 = ICNN(Xref)
    __shared__ float z1s[H], z2s[H];
    const float x0 = Xref[0], x1 = Xref[1];
    if (t < H) {
        float a = W1[2 * t] * x0 + W1[2 * t + 1] * x1 + b1[t];
        float e = expf(-fabsf(a));
        z1s[t] = logf(1.0f + e) + fmaxf(a, 0.0f);
    }
    __syncthreads();
    if (t < H) {
        float a = b2[t] + Wim2[2 * t] * x0 + Wim2[2 * t + 1] * x1;
        for (int i2 = 0; i2 < H; ++i2) a += W2[t * H + i2] * z1s[i2];
        float e = expf(-fabsf(a));
        z2s[t] = logf(1.0f + e) + fmaxf(a, 0.0f);
    }
    __syncthreads();
    if (t == 0) {
        float a = b3[0] + Wim3[0] * x0 + Wim3[1] * x1;
        for (int j2 = 0; j2 < H; ++j2) a += W3[j2] * z2s[j2];
        float e = expf(-fabsf(a));
        h0o[0] = logf(1.0f + e) + fmaxf(a, 0.0f);
    }
}

static __device__ __forceinline__ f32x4 mfma16(uint4v a, uint4v b, f32x4 c) {
    return __builtin_amdgcn_mfma_f32_16x16x32_bf16(
        __builtin_bit_cast(bf16x8, a), __builtin_bit_cast(bf16x8, b), c, 0, 0, 0);
}

// 3-level bf16 truncation split of 8 f32 -> three packed fragments
static __device__ __forceinline__ void split3(const float* v, uint4v& f0, uint4v& f1, uint4v& f2) {
    unsigned a[8], b[8], c[8];
#pragma unroll
    for (int e = 0; e < 8; ++e) {
        unsigned u0 = __float_as_uint(v[e]) & 0xFFFF0000u;
        float r1 = v[e] - __uint_as_float(u0);
        unsigned u1 = __float_as_uint(r1) & 0xFFFF0000u;
        float r2 = r1 - __uint_as_float(u1);
        unsigned u2 = __float_as_uint(r2) & 0xFFFF0000u;
        a[e] = u0; b[e] = u1; c[e] = u2;
    }
#pragma unroll
    for (int d = 0; d < 4; ++d) {
        f0[d] = (a[2 * d] >> 16) | (a[2 * d + 1] & 0xFFFF0000u);
        f1[d] = (b[2 * d] >> 16) | (b[2 * d + 1] & 0xFFFF0000u);
        f2[d] = (c[2 * d] >> 16) | (c[2 * d + 1] & 0xFFFF0000u);
    }
}

// sum across the 4 lanes {L, L^16, L^32, L^48} (same lane&15)
static __device__ __forceinline__ float redg(float v) {
    v += __shfl_xor(v, 16, 64);
    v += __shfl_xor(v, 32, 64);
    return v;
}

// ---------------------------------------------------------------------------
// Main kernel: 4 waves/block, 64 samples/wave (4 batches of 16).
// Per batch: GEMM1 C[j][s]=sum_i W2[j][i] z1[s][i] via 6-product 3-split MFMA
// (sample = lane&15 on the C column axis -> reductions are 2 shfl_xor).
// t staged j-major in per-wave LDS, re-read in B-fragment order for GEMM2
// C[i][s]=sum_j W2[j][i] t[s][j]. Two phases so only one GEMM's W2-fragments
// (96 regs) are pinned at a time; MFMA reads A/B from AGPRs natively, so
// AGPR placement of the fragment arrays is free.
// ---------------------------------------------------------------------------
__global__ __launch_bounds__(256, 2) void dho_main(
    const float* __restrict__ X, const float* __restrict__ U,
    const void* __restrict__ wsv,
    const float* __restrict__ W_fnn, const float* __restrict__ W_gnn,
    const float* __restrict__ b_gnn, const float* __restrict__ b3,
    const float* __restrict__ Wim3, const float* __restrict__ Xref,
    float* __restrict__ out, int N)
{
    const unsigned short* A1 = (const unsigned short*)wsv;
    const unsigned short* A2 = A1 + WS_A2_US;
    const float4* jcp = (const float4*)((const char*)wsv + WS_JC_B);
    const float4* wbp = (const float4*)((const char*)wsv + WS_WB_B);
    const float h0 = *(const float*)((const char*)wsv + WS_H0_B);

    __shared__ float tbuf[16 * 1088];   // [wave*4+beta][64 j][17 (16 samples + pad)]

    const int tid = threadIdx.x;
    const int w  = tid >> 6;
    const int L  = tid & 63;
    const int g  = L >> 4;
    const int lm = L & 15;
    const int base = blockIdx.x * 256 + w * 64;
    float* tb0 = tbuf + w * 4 * 1088;

    const float xr0 = Xref[0], xr1 = Xref[1];
    const float wim3_0 = Wim3[0], wim3_1 = Wim3[1];
    const float b3v = b3[0];
    const float fn0 = W_fnn[0], fn1 = W_fnn[1], fn2 = W_fnn[2], fn3 = W_fnn[3];
    const float gn0 = W_gnn[0], gn1 = W_gnn[1], gn2 = W_gnn[2], gn3 = W_gnn[3];
    const float bg0 = b_gnn[0], bg1 = b_gnn[1];

    float mX0[4], mX1[4], mU[4], mS3[4], mSigp[4], mV[4], mQA[4], mQB[4];

    // ---- pin GEMM1 fragments ----
    uint4v Af[3][4][2];
#pragma unroll
    for (int s = 0; s < 3; ++s)
#pragma unroll
        for (int tl = 0; tl < 4; ++tl)
#pragma unroll
            for (int kt = 0; kt < 2; ++kt)
                Af[s][tl][kt] = ((const uint4v*)A1)[((s * 4 + tl) * 2 + kt) * 64 + L];

    // ---- phase 1: forward ----
#pragma unroll
    for (int beta = 0; beta < 4; ++beta) {
        int sid = base + 16 * beta + lm;
        int sc = sid < N ? sid : N - 1;
        float2 x = ((const float2*)X)[sc];
        mX0[beta] = x.x; mX1[beta] = x.y; mU[beta] = U[sc];

        uint4v Zf[3][2];
#pragma unroll
        for (int kt = 0; kt < 2; ++kt) {
            float zv[8];
#pragma unroll
            for (int b = 0; b < 8; ++b) {
                int i = 32 * kt + 8 * g + b;
                float4 wv = wbp[i];
                float a1 = fmaf(wv.x, x.x, fmaf(wv.y, x.y, wv.z));
                float e1 = __expf(-fabsf(a1));
                float z = __logf(1.0f + e1) + fmaxf(a1, 0.0f);
                zv[b] = (i < H) ? z : 0.0f;
            }
            split3(zv, Zf[0][kt], Zf[1][kt], Zf[2][kt]);
        }

        float a3p = 0.0f, q0p = 0.0f, q1p = 0.0f;
        float* tb = tb0 + beta * 1088;
#pragma unroll
        for (int jt = 0; jt < 4; ++jt) {
            f32x4 acc = {0.0f, 0.0f, 0.0f, 0.0f};
#pragma unroll
            for (int kt = 0; kt < 2; ++kt) {
                acc = mfma16(Af[0][jt][kt], Zf[0][kt], acc);
                acc = mfma16(Af[0][jt][kt], Zf[1][kt], acc);
                acc = mfma16(Af[1][jt][kt], Zf[0][kt], acc);
                acc = mfma16(Af[0][jt][kt], Zf[2][kt], acc);
                acc = mfma16(Af[1][jt][kt], Zf[1][kt], acc);
                acc = mfma16(Af[2][jt][kt], Zf[0][kt], acc);
            }
#pragma unroll
            for (int r = 0; r < 4; ++r) {
                int j = 16 * jt + 4 * g + r;
                float4 jc = jcp[j];
                float a2 = acc[r] + jc.x + jc.y * x.x + jc.z * x.y;
                float e = __expf(-fabsf(a2));
                float inv = __builtin_amdgcn_rcpf(1.0f + e);
                float z2 = __logf(1.0f + e) + fmaxf(a2, 0.0f);
                float s2 = (a2 >= 0.0f ? 1.0f : e) * inv;
                a3p = fmaf(jc.w, z2, a3p);
                float tv = jc.w * s2;
                q0p = fmaf(tv, jc.y, q0p);
                q1p = fmaf(tv, jc.z, q1p);
                tb[j * 17 + lm] = tv;
            }
        }
        float a3 = redg(a3p) + b3v + wim3_0 * x.x + wim3_1 * x.y;
        float q0 = redg(q0p), q1 = redg(q1p);
        float e3 = __expf(-fabsf(a3));
        float inv3 = __builtin_amdgcn_rcpf(1.0f + e3);
        float hX = __logf(1.0f + e3) + fmaxf(a3, 0.0f);
        float s3 = (a3 >= 0.0f ? 1.0f : e3) * inv3;
        float h = hX - h0;
        float sigma, sigp;
        if (h >= 1.0f)      { sigma = h - 0.5f;      sigp = 1.0f; }
        else if (h > 0.0f)  { sigma = 0.5f * h * h;  sigp = h; }
        else                { sigma = 0.0f;          sigp = 0.0f; }
        float dx0 = x.x - xr0, dx1 = x.y - xr1;
        mV[beta] = sigma + EPSC * (dx0 * dx0 + dx1 * dx1);
        mS3[beta] = s3; mSigp[beta] = sigp;
        mQA[beta] = wim3_0 + q0; mQB[beta] = wim3_1 + q1;
    }

    // ---- pin GEMM2 fragments (reuse Af) ----
#pragma unroll
    for (int s = 0; s < 3; ++s)
#pragma unroll
        for (int tl = 0; tl < 4; ++tl)
#pragma unroll
            for (int kt = 0; kt < 2; ++kt)
                Af[s][tl][kt] = ((const uint4v*)A2)[((s * 4 + tl) * 2 + kt) * 64 + L];

    // ---- phase 2: backward + epilogue ----
#pragma unroll
    for (int beta = 0; beta < 4; ++beta) {
        int sid = base + 16 * beta + lm;
        float x0 = mX0[beta], x1 = mX1[beta];
        float* tb = tb0 + beta * 1088;
        uint4v Tf[3][2];
#pragma unroll
        for (int kt = 0; kt < 2; ++kt) {
            float tv[8];
#pragma unroll
            for (int b = 0; b < 8; ++b) {
                int j = 32 * kt + 8 * g + b;
                tv[b] = tb[j * 17 + lm];
            }
            split3(tv, Tf[0][kt], Tf[1][kt], Tf[2][kt]);
        }
        float p0 = 0.0f, p1 = 0.0f;
#pragma unroll
        for (int it = 0; it < 4; ++it) {
            f32x4 acc = {0.0f, 0.0f, 0.0f, 0.0f};
#pragma unroll
            for (int kt = 0; kt < 2; ++kt) {
                acc = mfma16(Af[0][it][kt], Tf[0][kt], acc);
                acc = mfma16(Af[0][it][kt], Tf[1][kt], acc);
                acc = mfma16(Af[1][it][kt], Tf[0][kt], acc);
                acc = mfma16(Af[0][it][kt], Tf[2][kt], acc);
                acc = mfma16(Af[1][it][kt], Tf[1][kt], acc);
                acc = mfma16(Af[2][it][kt], Tf[0][kt], acc);
            }
#pragma unroll
            for (int r = 0; r < 4; ++r) {
                int i = 16 * it + 4 * g + r;
                float4 wv = wbp[i];
                float a1 = fmaf(wv.x, x0, fmaf(wv.y, x1, wv.z));
                float e1 = __expf(-fabsf(a1));
                float s1 = (a1 >= 0.0f ? 1.0f : e1) * __builtin_amdgcn_rcpf(1.0f + e1);
                float c = acc[r] * s1;       // pads: acc=0 -> c=0
                p0 = fmaf(c, wv.x, p0);
                p1 = fmaf(c, wv.y, p1);
            }
        }
        float sum0 = redg(p0), sum1 = redg(p1);
        float s3 = mS3[beta], sigp = mSigp[beta];
        float dh0 = s3 * (mQA[beta] + sum0);
        float dh1 = s3 * (mQB[beta] + sum1);
        float dx0 = x0 - xr0, dx1 = x1 - xr1;
        float dV0 = sigp * dh0 + 2.0f * EPSC * dx0;
        float dV1 = sigp * dh1 + 2.0f * EPSC * dx1;
        float f0 = fn0 * x0 + fn1 * x1;
        float f1 = fn2 * x0 + fn3 * x1;
        float gg0 = gn0 * x0 + gn1 * x1 + bg0;
        float gg1 = gn2 * x0 + gn3 * x1 + bg1;
        float scv = dV0 * f0 + dV1 * f1 + ALPHAC * mV[beta] - fabsf(dV0 * gg0 + dV1 * gg1);
        float nrm = dV0 * dV0 + dV1 * dV1;
        float rr = fmaxf(scv, 0.0f) * __builtin_amdgcn_rcpf(nrm);
        float o0 = f0 - dV0 * rr + gg0 * mU[beta];
        float o1 = f1 - dV1 * rr + gg1 * mU[beta];
        if (g == 0 && sid < N) ((float2*)out)[sid] = make_float2(o0, o1);
    }
}

extern "C" void kernel_launch(void* const* d_in, const int* in_sizes, int n_in,
                              void* d_out, int out_size, void* d_ws, size_t ws_size,
                              hipStream_t stream) {
    // 0:X 1:U 2:Xref 3:W_fnn 4:W_gnn 5:b_gnn 6:W1 7:b1 8:W2 9:b2 10:W3 11:b3 12:Wim2 13:Wim3
    const float* X     = (const float*)d_in[0];
    const float* U     = (const float*)d_in[1];
    const float* Xref  = (const float*)d_in[2];
    const float* W_fnn = (const float*)d_in[3];
    const float* W_gnn = (const float*)d_in[4];
    const float* b_gnn = (const float*)d_in[5];
    const float* W1    = (const float*)d_in[6];
    const float* b1    = (const float*)d_in[7];
    const float* W2    = (const float*)d_in[8];
    const float* b2    = (const float*)d_in[9];
    const float* W3    = (const float*)d_in[10];
    const float* b3    = (const float*)d_in[11];
    const float* Wim2  = (const float*)d_in[12];
    const float* Wim3  = (const float*)d_in[13];

    const int N = in_sizes[0] / 2;
    float* outp = (float*)d_out;

    dho_prep<<<1, 256, 0, stream>>>(Xref, W1, b1, W2, b2, W3, b3, Wim2, Wim3, d_ws);

    const int blocks = (N + 255) / 256;
    dho_main<<<blocks, 256, 0, stream>>>(
        X, U, d_ws, W_fnn, W_gnn, b_gnn, b3, Wim3, Xref, outp, N);
}